// Round 1
// baseline (951.337 us; speedup 1.0000x reference)
//
#include <hip/hip_runtime.h>

// PRNNLayer: B=4096 independent sequential chains over T=2048 steps, 5 states.
// Mapping: one thread per chain; 64 blocks x 64 threads = 64 waves spread
// across CUs (1 wave/SIMD). Trans-pipe bound (~30 v_exp/v_rcp per step).

#define NB 4096
#define NT 2048
#define CHUNK 16
#define NCHUNK (NT / CHUNK)  // 128

// sigma(10x) = 1/(1+exp(-10x)) ; exp via hw exp2, clamped so e stays finite
// (avoids inf*0=NaN when states are ~1000 away from a threshold).
__device__ __forceinline__ float sig10(float x) {
    float a = fminf(fmaxf(-14.426950408889634f * x, -126.0f), 126.0f);
    return __builtin_amdgcn_rcpf(1.0f + __builtin_amdgcn_exp2f(a));
}
__device__ __forceinline__ float fexp(float x) {
    float a = fminf(fmaxf(1.4426950408889634f * x, -126.0f), 126.0f);
    return __builtin_amdgcn_exp2f(a);
}
__device__ __forceinline__ float clip1e5(float x) {
    return fminf(fmaxf(x, -100000.0f), 100000.0f);
}

__global__ __launch_bounds__(64, 1)
void prnn_kernel(const float* __restrict__ inp, const float* __restrict__ theta,
                 float* __restrict__ out) {
    const int b = blockIdx.x * 64 + threadIdx.x;

    // theta scaling (uniform -> scalar loads)
    const float f_     = theta[0] * 0.1f;
    const float smax_  = theta[1] * 1950.0f;
    const float qmax_  = theta[2] * 50.0f;
    const float ddf_   = theta[3] * 5.0f;
    const float tmin_  = theta[4] * -3.0f;
    const float tmax_  = theta[5] * 3.0f;
    const float Kc_    = theta[6] * 0.5f;
    const float SCmax_ = theta[7] * 1.5f;
    const float spmax_ = theta[8] * 1950.0f;
    const float qpmax_ = theta[9] * 40.0f;
    const float kp     = theta[10];
    const float sgmax_ = theta[11] * 1950.0f;
    const float qgmax_ = theta[12] * 40.0f;
    const float Kl_    = theta[13] * 0.5f;
    const float Kn_    = theta[14] * 0.5f;
    const float Dc     = 0.986f * 0.862f;
    const float inv_smax = __builtin_amdgcn_rcpf(smax_);

    const float* ip = inp + (size_t)b * (NT * 3);
    float*       op = out + (size_t)b * (NT * 5);

    float s0 = 0.f, s1 = 0.f, s2 = 0.f, s3 = 0.f, s4 = 0.f;

    // register double-buffered input staging: 16 steps * 3 floats per buffer
    float bufA[CHUNK * 3];
    float bufB[CHUNK * 3];

    auto prefetch = [&](float* dst, int c) {
        const float4* src = (const float4*)(ip + (size_t)c * (CHUNK * 3));
        float4* d4 = (float4*)dst;
        #pragma unroll
        for (int i = 0; i < (CHUNK * 3) / 4; ++i) d4[i] = src[i];
    };

    auto do_chunk = [&](const float* ib, int c) {
        float ob[CHUNK * 5];
        #pragma unroll
        for (int s = 0; s < CHUNK; ++s) {
            const float p  = ib[s * 3 + 0];
            const float tm = ib[s * 3 + 1];
            const float dl = ib[s * 3 + 2];

            const float pe = 29.8f * (dl * 24.0f) * 0.611f
                             * fexp(17.3f * tm * __builtin_amdgcn_rcpf(tm + 237.3f))
                             * __builtin_amdgcn_rcpf(tm + 273.2f);

            const float day   = sig10(dl - 0.5f);
            const float night = 1.0f - day;   // hv(-x) == 1 - hv(x)
            const float scmax_t = day * (SCmax_ * 2.0f) + night * (SCmax_ * 0.6f);
            const float lai_t   = day * 0.478f + night * 0.15f;
            const float kc_t    = day * Kc_ + night * (Kc_ * 0.4f);

            const float a   = sig10(p - 0.1f);
            const float h0  = sig10(s0);
            const float hsc = sig10(s0 - scmax_t);
            const float pintc = a * (h0 * hsc * p + (1.0f - hsc) * kc_t * Dc * lai_t);

            const float hsn   = sig10(tmin_ - tm);
            const float psnow = hsn * p;
            const float prain = (1.0f - hsn) * p;

            const float hm   = sig10(tm - tmax_);
            const float h1   = sig10(s1);
            const float melt = hm * h1 * fminf(s1, ddf_ * (tm - tmax_));

            const float h2    = sig10(s2);
            const float h2p   = sig10(s2 - spmax_);
            const float qpref = h2 * (h2p * qpmax_
                              + (1.0f - h2p) * (kp * p) * fexp(-f_ * (spmax_ - s2)));

            const float h3   = sig10(s3);
            const float h3s  = sig10(s3 - smax_);
            const float et   = h3 * (h3s * pe + (1.0f - h3s) * pe * (s3 * inv_smax));
            const float qsub = h3 * (h3s * qmax_
                             + (1.0f - h3s) * qmax_ * fexp(-f_ * (smax_ - s3)));
            const float qout = h3 * h3s * (s3 - smax_);

            const float h4    = sig10(s4);
            const float h4s   = sig10(s4 - sgmax_);
            const float qslow = h4 * (h4s * qgmax_
                              + (1.0f - h4s) * (p * Kl_ + p * p * Kn_)
                                * fexp(-f_ * (sgmax_ - s4)));

            s0 += clip1e5(pintc);
            s1 += clip1e5(psnow - melt);
            s2 += clip1e5(qpref);
            s3 += clip1e5(prain + melt - et - qsub - qout);
            s4 += clip1e5(qslow);

            ob[s * 5 + 0] = s0;
            ob[s * 5 + 1] = s1;
            ob[s * 5 + 2] = s2;
            ob[s * 5 + 3] = s3;
            ob[s * 5 + 4] = s4;
        }
        float4* dst = (float4*)(op + (size_t)c * (CHUNK * 5));
        const float4* src = (const float4*)ob;
        #pragma unroll
        for (int i = 0; i < (CHUNK * 5) / 4; ++i) dst[i] = src[i];
    };

    prefetch(bufA, 0);
    for (int c = 0; c < NCHUNK; c += 2) {
        prefetch(bufB, c + 1);          // loads in flight during chunk c compute
        do_chunk(bufA, c);
        if (c + 2 < NCHUNK) prefetch(bufA, c + 2);
        do_chunk(bufB, c + 1);
    }
}

extern "C" void kernel_launch(void* const* d_in, const int* in_sizes, int n_in,
                              void* d_out, int out_size, void* d_ws, size_t ws_size,
                              hipStream_t stream) {
    const float* inp   = (const float*)d_in[0];
    const float* theta = (const float*)d_in[1];
    float* out = (float*)d_out;
    prnn_kernel<<<NB / 64, 64, 0, stream>>>(inp, theta, out);
}

// Round 2
// 768.854 us; speedup vs baseline: 1.2373x; 1.2373x over previous
//
#include <hip/hip_runtime.h>

// PRNNLayer: B=4096 independent sequential chains over T=2048 steps, 5 states.
// One thread per chain; 64 blocks x 64 threads = 64 waves, 1 wave/SIMD.
// Issue-bound on the single wave per SIMD (R1: VALUBusy 5.15% vs 6.25%
// structural ceiling). R2: algebraic trans reduction — fused reciprocals
// (sigma(a)*sigma(b) = rcp(da*db)), no sigmoid clamps, folded exp2 args.

#define NB 4096
#define NT 2048
#define CHUNK 16
#define NCHUNK (NT / CHUNK)  // 128

#define L2E10 14.4269504089f  // 10*log2(e)  (hv(x) = sigmoid(10x))
#define L2E    1.44269504089f

__device__ __forceinline__ float rcpf(float x) { return __builtin_amdgcn_rcpf(x); }
__device__ __forceinline__ float ex2(float a)  { return __builtin_amdgcn_exp2f(a); }
// clamped exp2: only needed where e appears as a numerator multiplier and the
// argument can exceed fp32 overflow (state-threshold sigmoids). Clamp at 80:
// e<=2^80, d=1+e<=2^80, e/d -> 1 exactly as in the saturated reference.
__device__ __forceinline__ float ex2c(float a) { return __builtin_amdgcn_exp2f(fminf(a, 80.0f)); }
__device__ __forceinline__ float clip1e5(float x) {
    return __builtin_amdgcn_fmed3f(x, -100000.0f, 100000.0f);
}

__global__ __launch_bounds__(64, 1)
void prnn_kernel(const float* __restrict__ inp, const float* __restrict__ theta,
                 float* __restrict__ out) {
    const int b = blockIdx.x * 64 + threadIdx.x;

    // ---- theta (wave-uniform -> scalar regs), all constant-folded ----
    const float f_     = theta[0] * 0.1f;
    const float smax_  = theta[1] * 1950.0f;
    const float qmax_  = theta[2] * 50.0f;
    const float ddf_   = theta[3] * 5.0f;
    const float tmin_  = theta[4] * -3.0f;
    const float tmax_  = theta[5] * 3.0f;
    const float Kc_    = theta[6] * 0.5f;
    const float SCmax_ = theta[7] * 1.5f;
    const float spmax_ = theta[8] * 1950.0f;
    const float qpmax_ = theta[9] * 40.0f;
    const float kp     = theta[10];
    const float sgmax_ = theta[11] * 1950.0f;
    const float qgmax_ = theta[12] * 40.0f;
    const float Kl_    = theta[13] * 0.5f;
    const float Kn_    = theta[14] * 0.5f;

    const float inv_smax = rcpf(smax_);
    const float KcDc  = Kc_ * 0.849932f;          // Kc_ * 0.986*0.862
    const float c_sn  = -L2E10 * tmin_;           // esn arg = L2E10*tm + c_sn
    const float c_m   =  L2E10 * tmax_;           // em  arg = -L2E10*tm + c_m
    const float c_dd  = -ddf_ * tmax_;            // ddf*(tm-tmax) = fma(ddf,tm,c_dd)
    const float c_sc1 =  L2E10 * SCmax_ * 1.4f;   // scmax_t = SCmax_*(0.6+1.4*day)
    const float c_sc0 =  L2E10 * SCmax_ * 0.6f;
    const float c_2p  =  L2E10 * spmax_;
    const float c_3s  =  L2E10 * smax_;
    const float c_4s  =  L2E10 * sgmax_;
    const float fE    = f_ * L2E;
    const float c_E2  = -fE * spmax_;
    const float c_E3  = -fE * smax_;
    const float c_E4  = -fE * sgmax_;

    const float* ip = inp + (size_t)b * (NT * 3);
    float*       op = out + (size_t)b * (NT * 5);

    float s0 = 0.f, s1 = 0.f, s2 = 0.f, s3 = 0.f, s4 = 0.f;

    float bufA[CHUNK * 3];
    float bufB[CHUNK * 3];

    auto prefetch = [&](float* dst, int c) {
        const float4* src = (const float4*)(ip + (size_t)c * (CHUNK * 3));
        float4* d4 = (float4*)dst;
        #pragma unroll
        for (int i = 0; i < (CHUNK * 3) / 4; ++i) d4[i] = src[i];
    };

    auto do_chunk = [&](const float* ib, int c) {
        float ob[CHUNK * 5];
        #pragma unroll
        for (int s = 0; s < CHUNK; ++s) {
            const float p  = ib[s * 3 + 0];
            const float tm = ib[s * 3 + 1];
            const float dl = ib[s * 3 + 2];

            // pet: one rcp for both denominators
            const float A1 = tm + 237.3f;
            const float A2 = tm + 273.2f;
            const float q  = rcpf(A1 * A2);
            const float pe = 436.98672f * dl * ex2(24.958624f * tm * (q * A2)) * (q * A1);

            // day; night folded away (affine in day)
            const float day = rcpf(1.0f + ex2(fmaf(-L2E10, dl, 7.21347520f)));
            const float lai   = fmaf(0.328f, day, 0.15f);      // lai_t
            const float kcf   = fmaf(0.6f, day, 0.4f);         // kc_t = Kc_*kcf
            const float kterm = KcDc * kcf * lai;              // kc_t*Dc*lai_t

            // pintc = a*h0*hsc*p + a*(1-hsc)*kterm = R*(p + d0*esc*kterm)
            const float ea  = ex2(fmaf(-L2E10, p, L2E));       // -14.43*(p-0.1)
            const float da  = 1.0f + ea;
            const float e0  = ex2(-L2E10 * s0);
            const float d0  = 1.0f + e0;
            const float esc = ex2c(fmaf(c_sc1, day, fmaf(-L2E10, s0, c_sc0)));
            const float dsc = 1.0f + esc;
            const float Rp  = rcpf(da * d0 * dsc);
            const float pintc = Rp * fmaf(d0 * esc, kterm, p);

            // snow partition: prain = p - psnow (exact complement)
            const float psnow = rcpf(1.0f + ex2(fmaf(L2E10, tm, c_sn))) * p;
            const float prain = p - psnow;

            // melt = hm*h1*min(s1, ddf*(tm-tmax)) = rcp(dm*d1)*min(...)
            const float em = ex2(fmaf(-L2E10, tm, c_m));
            const float e1 = ex2(-L2E10 * s1);
            const float melt = rcpf((1.0f + em) * (1.0f + e1))
                               * fminf(s1, fmaf(ddf_, tm, c_dd));

            // qpref = R2*(qpmax + e2p*E2*kp*p)
            const float e2  = ex2(-L2E10 * s2);
            const float e2p = ex2c(fmaf(-L2E10, s2, c_2p));
            const float R2  = rcpf((1.0f + e2) * (1.0f + e2p));
            const float E2  = ex2(fmaf(fE, s2, c_E2));
            const float qpref = R2 * fmaf(e2p * E2, kp * p, qpmax_);

            // s3 fluxes combined: et+qsub+qout = R3*(pe*(1+e3s*s3/smax)
            //                                   + qmax*(1+e3s*E3) + (s3-smax))
            const float e3  = ex2(-L2E10 * s3);
            const float e3s = ex2c(fmaf(-L2E10, s3, c_3s));
            const float R3  = rcpf((1.0f + e3) * (1.0f + e3s));
            const float E3  = ex2(fmaf(fE, s3, c_E3));
            const float t_et = pe * fmaf(e3s * s3, inv_smax, 1.0f);
            const float t_qs = qmax_ * fmaf(e3s, E3, 1.0f);
            const float outflux = R3 * (t_et + t_qs + (s3 - smax_));
            const float ds3 = prain + melt - outflux;

            // qslow = R4*(qgmax + e4s*E4*(p*Kl + p*p*Kn))
            const float e4  = ex2(-L2E10 * s4);
            const float e4s = ex2c(fmaf(-L2E10, s4, c_4s));
            const float R4  = rcpf((1.0f + e4) * (1.0f + e4s));
            const float E4  = ex2(fmaf(fE, s4, c_E4));
            const float pl  = p * fmaf(p, Kn_, Kl_);
            const float qslow = R4 * fmaf(e4s * E4, pl, qgmax_);

            s0 += clip1e5(pintc);
            s1 += clip1e5(psnow - melt);
            s2 += clip1e5(qpref);
            s3 += clip1e5(ds3);
            s4 += clip1e5(qslow);

            ob[s * 5 + 0] = s0;
            ob[s * 5 + 1] = s1;
            ob[s * 5 + 2] = s2;
            ob[s * 5 + 3] = s3;
            ob[s * 5 + 4] = s4;
        }
        float4* dst = (float4*)(op + (size_t)c * (CHUNK * 5));
        const float4* src = (const float4*)ob;
        #pragma unroll
        for (int i = 0; i < (CHUNK * 5) / 4; ++i) dst[i] = src[i];
    };

    prefetch(bufA, 0);
    for (int c = 0; c < NCHUNK; c += 2) {
        prefetch(bufB, c + 1);
        do_chunk(bufA, c);
        if (c + 2 < NCHUNK) prefetch(bufA, c + 2);
        do_chunk(bufB, c + 1);
    }
}

extern "C" void kernel_launch(void* const* d_in, const int* in_sizes, int n_in,
                              void* d_out, int out_size, void* d_ws, size_t ws_size,
                              hipStream_t stream) {
    const float* inp   = (const float*)d_in[0];
    const float* theta = (const float*)d_in[1];
    float* out = (float*)d_out;
    prnn_kernel<<<NB / 64, 64, 0, stream>>>(inp, theta, out);
}